// Round 13
// baseline (1614.733 us; speedup 1.0000x reference)
//
#include <hip/hip_runtime.h>

#define B 32
#define S 2048
#define I 256
#define H 256

#define NWORK  64     // GEMM worker blocks (bid 0..63)
#define NRNN   16     // RNN blocks (bid 64..79), TWO batches each
#define NTILE  1024   // 512 M-tiles x 2 N-tiles
#define NFLAG  512    // 32 batches x 16 s-chunks
#define PFD    8      // xw prefetch depth (steps)

typedef _Float16 h2 __attribute__((ext_vector_type(2)));
typedef float    f4 __attribute__((ext_vector_type(4)));

__device__ __forceinline__ float fdot2(h2 a, h2 b, float c) {
#if __has_builtin(__builtin_amdgcn_fdot2)
    return __builtin_amdgcn_fdot2(a, b, c, false);
#else
    return fmaf((float)a[1], (float)b[1], fmaf((float)a[0], (float)b[0], c));
#endif
}

__device__ __forceinline__ void nt_store4(float* p, float4 v) {
    __builtin_nontemporal_store(__builtin_bit_cast(f4, v), (f4*)p);
}

// lgkm-only workgroup barrier. imm 0xC07F = vmcnt(63) expcnt(7) lgkmcnt(0).
__device__ __forceinline__ void lds_barrier() {
    __asm__ __volatile__("" ::: "memory");
    __builtin_amdgcn_s_waitcnt(0xC07F);
    __builtin_amdgcn_s_barrier();
    __asm__ __volatile__("" ::: "memory");
}

__device__ __forceinline__ float fast_tanh(float x) {
#if __has_builtin(__builtin_amdgcn_exp2f) && __has_builtin(__builtin_amdgcn_rcpf)
    float e = __builtin_amdgcn_exp2f(x * 2.8853900818f);   // e^(2x)
    float r = __builtin_amdgcn_rcpf(e + 1.0f);
    return fmaf(-2.0f, r, 1.0f);
#else
    float e = __expf(2.0f * x);
    return 1.0f - __fdividef(2.0f, e + 1.0f);
#endif
}

__device__ __forceinline__ float dpp_xor1(float x) {
    return __builtin_bit_cast(float, __builtin_amdgcn_mov_dpp(
        __builtin_bit_cast(int, x), 0xB1, 0xF, 0xF, false));
}
__device__ __forceinline__ float dpp_xor2(float x) {
    return __builtin_bit_cast(float, __builtin_amdgcn_mov_dpp(
        __builtin_bit_cast(int, x), 0x4E, 0xF, 0xF, false));
}

// Acquire-poll until flag reaches 2; bounded so sync bugs -> wrong answer,
// never a hung container.
__device__ __forceinline__ void wait_flag(const int* f) {
    long long t0 = __builtin_amdgcn_s_memrealtime();
    while (__hip_atomic_load(f, __ATOMIC_ACQUIRE, __HIP_MEMORY_SCOPE_AGENT) != 2) {
        __builtin_amdgcn_s_sleep(8);
        if (__builtin_amdgcn_s_memrealtime() - t0 > 25000000LL) break;
    }
}

__global__ void zero_flags(int* flags) { flags[threadIdx.x] = 0; }

// ---------------------------------------------------------------------------
// GEMM tile body (unchanged from R12). NT xw stores.
// ---------------------------------------------------------------------------
#define TM 128
#define TN 128
#define TK 32
#define LDP (TM + 4)

__device__ __forceinline__ void gemm_tile(
    const float* __restrict__ x, const float* __restrict__ Wxw,
    const float* __restrict__ Wxb, float* __restrict__ out,
    float (*As)[LDP], float (*Bs)[LDP], int t, int m0, int n0)
{
    const int lr = t >> 3;
    const int lc = t & 7;
    const int tn = t & 15, tm = t >> 4;

    float acc[8][8] = {};
    float bias[8];
#pragma unroll
    for (int jj = 0; jj < 4; ++jj) {
        bias[jj]     = Wxb[n0 + 4 * tn + jj];
        bias[4 + jj] = Wxb[n0 + 64 + 4 * tn + jj];
    }

    float4 va[4], vb[4];
#pragma unroll
    for (int hh = 0; hh < 4; ++hh) {
        const int m = lr + 32 * hh;
        va[hh] = *(const float4*)(x   + (size_t)(m0 + m) * I + 4 * lc);
        vb[hh] = *(const float4*)(Wxw + (size_t)(n0 + m) * I + 4 * lc);
    }

    for (int kt = 0; kt < I; kt += TK) {
#pragma unroll
        for (int hh = 0; hh < 4; ++hh) {
            const int m = lr + 32 * hh;
            float4 v = va[hh];
            As[4 * lc + 0][m] = v.x; As[4 * lc + 1][m] = v.y;
            As[4 * lc + 2][m] = v.z; As[4 * lc + 3][m] = v.w;
            float4 wv = vb[hh];
            Bs[4 * lc + 0][m] = wv.x; Bs[4 * lc + 1][m] = wv.y;
            Bs[4 * lc + 2][m] = wv.z; Bs[4 * lc + 3][m] = wv.w;
        }
        lds_barrier();
        if (kt + TK < I) {
#pragma unroll
            for (int hh = 0; hh < 4; ++hh) {
                const int m = lr + 32 * hh;
                va[hh] = *(const float4*)(x   + (size_t)(m0 + m) * I + kt + TK + 4 * lc);
                vb[hh] = *(const float4*)(Wxw + (size_t)(n0 + m) * I + kt + TK + 4 * lc);
            }
        }
#pragma unroll
        for (int k = 0; k < TK; ++k) {
            float4 a0 = *(const float4*)&As[k][4 * tm];
            float4 a1 = *(const float4*)&As[k][4 * tm + 64];
            float4 b0 = *(const float4*)&Bs[k][4 * tn];
            float4 b1 = *(const float4*)&Bs[k][4 * tn + 64];
            float av[8] = {a0.x, a0.y, a0.z, a0.w, a1.x, a1.y, a1.z, a1.w};
            float bv[8] = {b0.x, b0.y, b0.z, b0.w, b1.x, b1.y, b1.z, b1.w};
#pragma unroll
            for (int i2 = 0; i2 < 8; ++i2)
#pragma unroll
                for (int jj = 0; jj < 8; ++jj)
                    acc[i2][jj] = fmaf(av[i2], bv[jj], acc[i2][jj]);
        }
        lds_barrier();
    }
#pragma unroll
    for (int hi = 0; hi < 2; ++hi) {
#pragma unroll
        for (int i2 = 0; i2 < 4; ++i2) {
            const int r = m0 + 64 * hi + 4 * tm + i2;
            float4 v0 = { acc[4 * hi + i2][0] + bias[0], acc[4 * hi + i2][1] + bias[1],
                          acc[4 * hi + i2][2] + bias[2], acc[4 * hi + i2][3] + bias[3] };
            float4 v1 = { acc[4 * hi + i2][4] + bias[4], acc[4 * hi + i2][5] + bias[5],
                          acc[4 * hi + i2][6] + bias[6], acc[4 * hi + i2][7] + bias[7] };
            nt_store4(out + (size_t)r * H + n0 + 4 * tn,      v0);
            nt_store4(out + (size_t)r * H + n0 + 64 + 4 * tn, v1);
        }
    }
}

// 16 fdot2 for one uint4 of h against 4 weight rows. U must be a
// compile-time constant (always used inside fully-unrolled loops).
#define MAC16(A0,A1,A2,A3,V,U) do {                                   \
    h2 c0 = __builtin_bit_cast(h2, (V).x);                            \
    h2 c1 = __builtin_bit_cast(h2, (V).y);                            \
    h2 c2 = __builtin_bit_cast(h2, (V).z);                            \
    h2 c3 = __builtin_bit_cast(h2, (V).w);                            \
    A0 = fdot2(wreg[0][4*(U)+0], c0, A0);                             \
    A0 = fdot2(wreg[0][4*(U)+1], c1, A0);                             \
    A0 = fdot2(wreg[0][4*(U)+2], c2, A0);                             \
    A0 = fdot2(wreg[0][4*(U)+3], c3, A0);                             \
    A1 = fdot2(wreg[1][4*(U)+0], c0, A1);                             \
    A1 = fdot2(wreg[1][4*(U)+1], c1, A1);                             \
    A1 = fdot2(wreg[1][4*(U)+2], c2, A1);                             \
    A1 = fdot2(wreg[1][4*(U)+3], c3, A1);                             \
    A2 = fdot2(wreg[2][4*(U)+0], c0, A2);                             \
    A2 = fdot2(wreg[2][4*(U)+1], c1, A2);                             \
    A2 = fdot2(wreg[2][4*(U)+2], c2, A2);                             \
    A2 = fdot2(wreg[2][4*(U)+3], c3, A2);                             \
    A3 = fdot2(wreg[3][4*(U)+0], c0, A3);                             \
    A3 = fdot2(wreg[3][4*(U)+1], c1, A3);                             \
    A3 = fdot2(wreg[3][4*(U)+2], c2, A3);                             \
    A3 = fdot2(wreg[3][4*(U)+3], c3, A3);                             \
} while (0)

// ---------------------------------------------------------------------------
// R13: TWO batches per RNN block. wreg (W in registers) is batch-independent
// and shared; ONE barrier/step covers both. Batch B's MAC issues while batch
// A's post-barrier LDS latency + butterfly/tanh tail would stall the SIMD:
// wall/2-steps ~ stall + 2*issue instead of 2*(stall+issue) -> ~700 cyc/step
// vs 969. vB reads interleaved mid-MACA (keeps peak v-liveness ~48 VGPR).
// Per-batch math bit-identical to R6-R12.
// ---------------------------------------------------------------------------
__device__ __forceinline__ void rnn_body2(
    const float* __restrict__ Whw, float* __restrict__ out,
    _Float16 (*hshA)[4][72], _Float16 (*hshB)[4][72],
    int bA, int bB, int t, const int* flagsA, const int* flagsB)
{
    const int w = t >> 6;        // wave: rows [64w, 64w+64)
    const int l = t & 63;
    const int j = l >> 2;        // quad: rows 64w+4j .. 64w+4j+3
    const int q = l & 3;         // k-quarter: k in [64q, 64q+64)

    // wreg[i][m] = W[64w+4j+(q^i)][64q + 2m .. 2m+1] as h2 (permuted rows).
    h2 wreg[4][32];
#pragma unroll
    for (int i = 0; i < 4; ++i) {
        const float4* wp =
            (const float4*)(Whw + (size_t)(64 * w + 4 * j + (q ^ i)) * H + 64 * q);
#pragma unroll
        for (int m = 0; m < 16; ++m) {
            float4 f = wp[m];
            wreg[i][2 * m]     = h2{(_Float16)f.x, (_Float16)f.y};
            wreg[i][2 * m + 1] = h2{(_Float16)f.z, (_Float16)f.w};
        }
    }
#pragma unroll
    for (int i = 0; i < 4; ++i)
#pragma unroll
        for (int m = 0; m < 32; ++m) {
            unsigned tmp = __builtin_bit_cast(unsigned, wreg[i][m]);
            __asm__("" : "+v"(tmp));
            wreg[i][m] = __builtin_bit_cast(h2, tmp);
        }

    hshA[0][w][l] = (_Float16)0.0f;
    hshB[0][w][l] = (_Float16)0.0f;
    __syncthreads();

    if (flagsA) {                       // gate initial xw reads on chunk 0
        if (t == 0) { wait_flag(flagsA + 0); wait_flag(flagsB + 0); }
        __syncthreads();
    }

    float* outbA = out + (size_t)bA * S * H + t;
    float* outbB = out + (size_t)bB * S * H + t;
    float *opA = outbA, *opB = outbB;

    // PFD-deep xw rings; tail reads stay in out[] bounds (values unused).
    float xrA[PFD], xrB[PFD];
#pragma unroll
    for (int i = 0; i < PFD; ++i) {
        xrA[i] = outbA[(size_t)i * H];
        xrB[i] = outbB[(size_t)i * H];
    }
    const float* lpA = outbA + (size_t)PFD * H;
    const float* lpB = outbB + (size_t)PFD * H;

    float hvA = 0.f, hvB = 0.f;
    for (int c = 0; c < 16; ++c) {       // 16 chunks x 128 steps
#pragma unroll 8
        for (int sl = 0; sl < 128; ++sl) {
            const int p  = sl & 1;           // static (128 % 8 == 0)
            const int rp = sl & (PFD - 1);
            if (sl == 120 && c < 15 && flagsA) {   // gate ring into chunk c+1
                if (t == 0) { wait_flag(flagsA + c + 1); wait_flag(flagsB + c + 1); }
                __syncthreads();
            }
            const uint4* hpA = (const uint4*)&hshA[p][q][0];
            const uint4* hpB = (const uint4*)&hshB[p][q][0];

            uint4 vA[8];
#pragma unroll
            for (int u = 0; u < 8; ++u) vA[u] = hpA[u];
            float xwA = xrA[rp], xwB = xrB[rp];
            xrA[rp] = lpA[0]; lpA += H;      // VM work fills read shadow
            xrB[rp] = lpB[0]; lpB += H;

            float aA0 = 0.f, aA1 = 0.f, aA2 = 0.f, aA3 = 0.f;
#pragma unroll
            for (int u = 0; u < 4; ++u) MAC16(aA0, aA1, aA2, aA3, vA[u], u);
            uint4 vB0[4];
#pragma unroll
            for (int u = 0; u < 4; ++u) vB0[u] = hpB[u];   // prefetch B (1st half)
#pragma unroll
            for (int u = 4; u < 8; ++u) MAC16(aA0, aA1, aA2, aA3, vA[u], u);
            uint4 vB1[4];
#pragma unroll
            for (int u = 0; u < 4; ++u) vB1[u] = hpB[u + 4]; // prefetch B (2nd half)

            float SaA  = aA0 + dpp_xor1(aA1);
            float SbA  = aA2 + dpp_xor1(aA3);
            float sumA = SaA + dpp_xor2(SbA);
            hvA = fast_tanh(xwA + sumA);
            hshA[p ^ 1][w][l] = (_Float16)hvA;
            opA[0] = hvA; opA += H;

            float aB0 = 0.f, aB1 = 0.f, aB2 = 0.f, aB3 = 0.f;
#pragma unroll
            for (int u = 0; u < 4; ++u) MAC16(aB0, aB1, aB2, aB3, vB0[u], u);
#pragma unroll
            for (int u = 4; u < 8; ++u) MAC16(aB0, aB1, aB2, aB3, vB1[u - 4], u);

            float SaB  = aB0 + dpp_xor1(aB1);
            float SbB  = aB2 + dpp_xor1(aB3);
            float sumB = SaB + dpp_xor2(SbB);
            hvB = fast_tanh(xwB + sumB);
            hshB[p ^ 1][w][l] = (_Float16)hvB;
            opB[0] = hvB; opB += H;

            lds_barrier();               // the ONE barrier per step (shared)
        }
    }
    out[(size_t)B * S * H + (size_t)bA * H + t] = hvA;   // h_last
    out[(size_t)B * S * H + (size_t)bB * H + t] = hvB;
}

// ---------------------------------------------------------------------------
// Fused persistent kernel, grid = 80 blocks.
//   blocks 0..63  : GEMM workers (dispatched first; never wait -> no deadlock)
//   blocks 64..79 : RNN, batches (2r, 2r+1) for r = bid-64
// ---------------------------------------------------------------------------
__global__ __launch_bounds__(256, 1) void fused_srnn(
    const float* __restrict__ x, const float* __restrict__ Wxw,
    const float* __restrict__ Wxb, const float* __restrict__ Whw,
    float* __restrict__ out, int* __restrict__ flags)
{
    __shared__ __align__(16) float As[TK][LDP];
    __shared__ __align__(16) float Bs[TK][LDP];
    __shared__ __align__(16) _Float16 hshA[2][4][72];
    __shared__ __align__(16) _Float16 hshB[2][4][72];

    const int bid = blockIdx.x;
    const int t   = threadIdx.x;

    if (bid < NWORK) {
        for (int tau = bid; tau < NTILE; tau += NWORK) {
            // s-major order: tau = st*64 + bb*2 + nt
            const int st = tau >> 6;
            const int bb = (tau >> 1) & 31;
            const int nt = tau & 1;
            gemm_tile(x, Wxw, Wxb, out, As, Bs, t,
                      bb * S + st * TM, nt * TN);
            __threadfence();
            __syncthreads();
            if (t == 0)
                __hip_atomic_fetch_add(&flags[bb * 16 + st], 1,
                                       __ATOMIC_RELEASE, __HIP_MEMORY_SCOPE_AGENT);
        }
        return;
    }
    const int r = bid - NWORK;
    rnn_body2(Whw, out, hshA, hshB, 2 * r, 2 * r + 1, t,
              flags + (2 * r) * 16, flags + (2 * r + 1) * 16);
}

// ---------------------------------------------------------------------------
// Fallback path (no workspace): two-kernel pipeline, same bodies.
// ---------------------------------------------------------------------------
__global__ __launch_bounds__(256) void phase1_gemm(
    const float* __restrict__ x, const float* __restrict__ Wxw,
    const float* __restrict__ Wxb, float* __restrict__ out)
{
    __shared__ __align__(16) float As[TK][LDP];
    __shared__ __align__(16) float Bs[TK][LDP];
    gemm_tile(x, Wxw, Wxb, out, As, Bs, threadIdx.x,
              blockIdx.x * TM, blockIdx.y * TN);
}

__global__ __launch_bounds__(256, 1) void phase2_rnn(
    const float* __restrict__ Whw, float* __restrict__ out)
{
    __shared__ __align__(16) _Float16 hshA[2][4][72];
    __shared__ __align__(16) _Float16 hshB[2][4][72];
    const int r = blockIdx.x;
    rnn_body2(Whw, out, hshA, hshB, 2 * r, 2 * r + 1, threadIdx.x,
              nullptr, nullptr);
}

// ---------------------------------------------------------------------------
extern "C" void kernel_launch(void* const* d_in, const int* in_sizes, int n_in,
                              void* d_out, int out_size, void* d_ws, size_t ws_size,
                              hipStream_t stream) {
    const float* x   = (const float*)d_in[0];
    const float* Wxw = (const float*)d_in[1];
    const float* Wxb = (const float*)d_in[2];
    const float* Whw = (const float*)d_in[3];
    float* out = (float*)d_out;

    if (d_ws != nullptr && ws_size >= NFLAG * sizeof(int)) {
        int* flags = (int*)d_ws;
        zero_flags<<<1, NFLAG, 0, stream>>>(flags);
        fused_srnn<<<NWORK + NRNN, 256, 0, stream>>>(x, Wxw, Wxb, Whw, out, flags);
    } else {
        dim3 g1(B * S / TM, H / TN);   // 512 x 2
        phase1_gemm<<<g1, 256, 0, stream>>>(x, Wxw, Wxb, out);
        phase2_rnn<<<NRNN, 256, 0, stream>>>(Whw, out);
    }
}

// Round 14
// 1598.666 us; speedup vs baseline: 1.0101x; 1.0101x over previous
//
#include <hip/hip_runtime.h>

#define B 32
#define S 2048
#define I 256
#define H 256

#define NWORK  64     // GEMM worker blocks (bid 0..63)
#define NRNN   16     // RNN blocks (bid 64..79), TWO batches each
#define NTILE  1024   // 512 M-tiles x 2 N-tiles
#define NFLAG  512    // 32 batches x 16 s-chunks
#define PFD    8      // xw prefetch depth (steps)

typedef _Float16 h2 __attribute__((ext_vector_type(2)));
typedef float    f4 __attribute__((ext_vector_type(4)));

__device__ __forceinline__ float fdot2(h2 a, h2 b, float c) {
#if __has_builtin(__builtin_amdgcn_fdot2)
    return __builtin_amdgcn_fdot2(a, b, c, false);
#else
    return fmaf((float)a[1], (float)b[1], fmaf((float)a[0], (float)b[0], c));
#endif
}

__device__ __forceinline__ void nt_store4(float* p, float4 v) {
    __builtin_nontemporal_store(__builtin_bit_cast(f4, v), (f4*)p);
}

// lgkm-only workgroup barrier. imm 0xC07F = vmcnt(63) expcnt(7) lgkmcnt(0).
__device__ __forceinline__ void lds_barrier() {
    __asm__ __volatile__("" ::: "memory");
    __builtin_amdgcn_s_waitcnt(0xC07F);
    __builtin_amdgcn_s_barrier();
    __asm__ __volatile__("" ::: "memory");
}

__device__ __forceinline__ float fast_tanh(float x) {
#if __has_builtin(__builtin_amdgcn_exp2f) && __has_builtin(__builtin_amdgcn_rcpf)
    float e = __builtin_amdgcn_exp2f(x * 2.8853900818f);   // e^(2x)
    float r = __builtin_amdgcn_rcpf(e + 1.0f);
    return fmaf(-2.0f, r, 1.0f);
#else
    float e = __expf(2.0f * x);
    return 1.0f - __fdividef(2.0f, e + 1.0f);
#endif
}

__device__ __forceinline__ float dpp_xor1(float x) {
    return __builtin_bit_cast(float, __builtin_amdgcn_mov_dpp(
        __builtin_bit_cast(int, x), 0xB1, 0xF, 0xF, false));
}
__device__ __forceinline__ float dpp_xor2(float x) {
    return __builtin_bit_cast(float, __builtin_amdgcn_mov_dpp(
        __builtin_bit_cast(int, x), 0x4E, 0xF, 0xF, false));
}

// Acquire-poll until flag reaches 2; bounded so sync bugs -> wrong answer,
// never a hung container.
__device__ __forceinline__ void wait_flag(const int* f) {
    long long t0 = __builtin_amdgcn_s_memrealtime();
    while (__hip_atomic_load(f, __ATOMIC_ACQUIRE, __HIP_MEMORY_SCOPE_AGENT) != 2) {
        __builtin_amdgcn_s_sleep(8);
        if (__builtin_amdgcn_s_memrealtime() - t0 > 25000000LL) break;
    }
}

__global__ void zero_flags(int* flags) { flags[threadIdx.x] = 0; }

// ---------------------------------------------------------------------------
// GEMM tile body (unchanged). NT xw stores.
// ---------------------------------------------------------------------------
#define TM 128
#define TN 128
#define TK 32
#define LDP (TM + 4)

__device__ __forceinline__ void gemm_tile(
    const float* __restrict__ x, const float* __restrict__ Wxw,
    const float* __restrict__ Wxb, float* __restrict__ out,
    float (*As)[LDP], float (*Bs)[LDP], int t, int m0, int n0)
{
    const int lr = t >> 3;
    const int lc = t & 7;
    const int tn = t & 15, tm = t >> 4;

    float acc[8][8] = {};
    float bias[8];
#pragma unroll
    for (int jj = 0; jj < 4; ++jj) {
        bias[jj]     = Wxb[n0 + 4 * tn + jj];
        bias[4 + jj] = Wxb[n0 + 64 + 4 * tn + jj];
    }

    float4 va[4], vb[4];
#pragma unroll
    for (int hh = 0; hh < 4; ++hh) {
        const int m = lr + 32 * hh;
        va[hh] = *(const float4*)(x   + (size_t)(m0 + m) * I + 4 * lc);
        vb[hh] = *(const float4*)(Wxw + (size_t)(n0 + m) * I + 4 * lc);
    }

    for (int kt = 0; kt < I; kt += TK) {
#pragma unroll
        for (int hh = 0; hh < 4; ++hh) {
            const int m = lr + 32 * hh;
            float4 v = va[hh];
            As[4 * lc + 0][m] = v.x; As[4 * lc + 1][m] = v.y;
            As[4 * lc + 2][m] = v.z; As[4 * lc + 3][m] = v.w;
            float4 wv = vb[hh];
            Bs[4 * lc + 0][m] = wv.x; Bs[4 * lc + 1][m] = wv.y;
            Bs[4 * lc + 2][m] = wv.z; Bs[4 * lc + 3][m] = wv.w;
        }
        lds_barrier();
        if (kt + TK < I) {
#pragma unroll
            for (int hh = 0; hh < 4; ++hh) {
                const int m = lr + 32 * hh;
                va[hh] = *(const float4*)(x   + (size_t)(m0 + m) * I + kt + TK + 4 * lc);
                vb[hh] = *(const float4*)(Wxw + (size_t)(n0 + m) * I + kt + TK + 4 * lc);
            }
        }
#pragma unroll
        for (int k = 0; k < TK; ++k) {
            float4 a0 = *(const float4*)&As[k][4 * tm];
            float4 a1 = *(const float4*)&As[k][4 * tm + 64];
            float4 b0 = *(const float4*)&Bs[k][4 * tn];
            float4 b1 = *(const float4*)&Bs[k][4 * tn + 64];
            float av[8] = {a0.x, a0.y, a0.z, a0.w, a1.x, a1.y, a1.z, a1.w};
            float bv[8] = {b0.x, b0.y, b0.z, b0.w, b1.x, b1.y, b1.z, b1.w};
#pragma unroll
            for (int i2 = 0; i2 < 8; ++i2)
#pragma unroll
                for (int jj = 0; jj < 8; ++jj)
                    acc[i2][jj] = fmaf(av[i2], bv[jj], acc[i2][jj]);
        }
        lds_barrier();
    }
#pragma unroll
    for (int hi = 0; hi < 2; ++hi) {
#pragma unroll
        for (int i2 = 0; i2 < 4; ++i2) {
            const int r = m0 + 64 * hi + 4 * tm + i2;
            float4 v0 = { acc[4 * hi + i2][0] + bias[0], acc[4 * hi + i2][1] + bias[1],
                          acc[4 * hi + i2][2] + bias[2], acc[4 * hi + i2][3] + bias[3] };
            float4 v1 = { acc[4 * hi + i2][4] + bias[4], acc[4 * hi + i2][5] + bias[5],
                          acc[4 * hi + i2][6] + bias[6], acc[4 * hi + i2][7] + bias[7] };
            nt_store4(out + (size_t)r * H + n0 + 4 * tn,      v0);
            nt_store4(out + (size_t)r * H + n0 + 64 + 4 * tn, v1);
        }
    }
}

// 16 fdot2 for one uint4 of h (read inline -- no staging regs) against 4
// weight rows. U compile-time constant.
#define MAC16(A0,A1,A2,A3,HP,U) do {                                  \
    uint4 v_ = (HP)[U];                                               \
    h2 c0 = __builtin_bit_cast(h2, v_.x);                             \
    h2 c1 = __builtin_bit_cast(h2, v_.y);                             \
    h2 c2 = __builtin_bit_cast(h2, v_.z);                             \
    h2 c3 = __builtin_bit_cast(h2, v_.w);                             \
    A0 = fdot2(wreg[0][4*(U)+0], c0, A0);                             \
    A0 = fdot2(wreg[0][4*(U)+1], c1, A0);                             \
    A0 = fdot2(wreg[0][4*(U)+2], c2, A0);                             \
    A0 = fdot2(wreg[0][4*(U)+3], c3, A0);                             \
    A1 = fdot2(wreg[1][4*(U)+0], c0, A1);                             \
    A1 = fdot2(wreg[1][4*(U)+1], c1, A1);                             \
    A1 = fdot2(wreg[1][4*(U)+2], c2, A1);                             \
    A1 = fdot2(wreg[1][4*(U)+3], c3, A1);                             \
    A2 = fdot2(wreg[2][4*(U)+0], c0, A2);                             \
    A2 = fdot2(wreg[2][4*(U)+1], c1, A2);                             \
    A2 = fdot2(wreg[2][4*(U)+2], c2, A2);                             \
    A2 = fdot2(wreg[2][4*(U)+3], c3, A2);                             \
    A3 = fdot2(wreg[3][4*(U)+0], c0, A3);                             \
    A3 = fdot2(wreg[3][4*(U)+1], c1, A3);                             \
    A3 = fdot2(wreg[3][4*(U)+2], c2, A3);                             \
    A3 = fdot2(wreg[3][4*(U)+3], c3, A3);                             \
} while (0)

// ---------------------------------------------------------------------------
// R14: 2-batch pairing, SCHEDULE FIXED vs R13:
//   bar -> MACA -> MACB -> (tailA || tailB) -> bar
// Both MACs read buffer p with no tail in between: fdot2 issue is continuous
// (1024 cyc) and both tails overlap each other after. No staging arrays
// (reads inline) -> peak liveness ~175 regs, no spill. Per-batch math is
// bit-identical to R6-R12.
// ---------------------------------------------------------------------------
__device__ __forceinline__ void rnn_body2(
    const float* __restrict__ Whw, float* __restrict__ out,
    _Float16 (*hshA)[4][72], _Float16 (*hshB)[4][72],
    int bA, int bB, int t, const int* flagsA, const int* flagsB)
{
    const int w = t >> 6;        // wave: rows [64w, 64w+64)
    const int l = t & 63;
    const int j = l >> 2;        // quad: rows 64w+4j .. 64w+4j+3
    const int q = l & 3;         // k-quarter: k in [64q, 64q+64)

    // wreg[i][m] = W[64w+4j+(q^i)][64q + 2m .. 2m+1] as h2 (permuted rows).
    h2 wreg[4][32];
#pragma unroll
    for (int i = 0; i < 4; ++i) {
        const float4* wp =
            (const float4*)(Whw + (size_t)(64 * w + 4 * j + (q ^ i)) * H + 64 * q);
#pragma unroll
        for (int m = 0; m < 16; ++m) {
            float4 f = wp[m];
            wreg[i][2 * m]     = h2{(_Float16)f.x, (_Float16)f.y};
            wreg[i][2 * m + 1] = h2{(_Float16)f.z, (_Float16)f.w};
        }
    }
#pragma unroll
    for (int i = 0; i < 4; ++i)
#pragma unroll
        for (int m = 0; m < 32; ++m) {
            unsigned tmp = __builtin_bit_cast(unsigned, wreg[i][m]);
            __asm__("" : "+v"(tmp));
            wreg[i][m] = __builtin_bit_cast(h2, tmp);
        }

    hshA[0][w][l] = (_Float16)0.0f;
    hshB[0][w][l] = (_Float16)0.0f;
    __syncthreads();

    if (flagsA) {                       // gate initial xw reads on chunk 0
        if (t == 0) { wait_flag(flagsA + 0); wait_flag(flagsB + 0); }
        __syncthreads();
    }

    float* outbA = out + (size_t)bA * S * H + t;
    float* outbB = out + (size_t)bB * S * H + t;
    float *opA = outbA, *opB = outbB;

    // PFD-deep xw rings; tail reads stay in out[] bounds (values unused).
    float xrA[PFD], xrB[PFD];
#pragma unroll
    for (int i = 0; i < PFD; ++i) {
        xrA[i] = outbA[(size_t)i * H];
        xrB[i] = outbB[(size_t)i * H];
    }
    const float* lpA = outbA + (size_t)PFD * H;
    const float* lpB = outbB + (size_t)PFD * H;

    float hvA = 0.f, hvB = 0.f;
    for (int c = 0; c < 16; ++c) {       // 16 chunks x 128 steps
#pragma unroll 8
        for (int sl = 0; sl < 128; ++sl) {
            const int p  = sl & 1;           // static (128 % 8 == 0)
            const int rp = sl & (PFD - 1);
            if (sl == 120 && c < 15 && flagsA) {   // gate ring into chunk c+1
                if (t == 0) { wait_flag(flagsA + c + 1); wait_flag(flagsB + c + 1); }
                __syncthreads();
            }
            const uint4* hpA = (const uint4*)&hshA[p][q][0];
            const uint4* hpB = (const uint4*)&hshB[p][q][0];

            float xwA = xrA[rp], xwB = xrB[rp];
            xrA[rp] = lpA[0]; lpA += H;      // ring refills (VM shadow)
            xrB[rp] = lpB[0]; lpB += H;

            // --- MACA then MACB back-to-back: continuous fdot2 issue ---
            float aA0 = 0.f, aA1 = 0.f, aA2 = 0.f, aA3 = 0.f;
#pragma unroll
            for (int u = 0; u < 8; ++u) MAC16(aA0, aA1, aA2, aA3, hpA, u);
            float aB0 = 0.f, aB1 = 0.f, aB2 = 0.f, aB3 = 0.f;
#pragma unroll
            for (int u = 0; u < 8; ++u) MAC16(aB0, aB1, aB2, aB3, hpB, u);

            // --- tails: independent DPP/tanh chains, interleave freely ---
            float SaA  = aA0 + dpp_xor1(aA1);
            float SbA  = aA2 + dpp_xor1(aA3);
            float SaB  = aB0 + dpp_xor1(aB1);
            float SbB  = aB2 + dpp_xor1(aB3);
            float sumA = SaA + dpp_xor2(SbA);
            float sumB = SaB + dpp_xor2(SbB);
            hvA = fast_tanh(xwA + sumA);
            hvB = fast_tanh(xwB + sumB);
            hshA[p ^ 1][w][l] = (_Float16)hvA;
            hshB[p ^ 1][w][l] = (_Float16)hvB;
            opA[0] = hvA; opA += H;
            opB[0] = hvB; opB += H;

            lds_barrier();               // the ONE barrier per step (shared)
        }
    }
    out[(size_t)B * S * H + (size_t)bA * H + t] = hvA;   // h_last
    out[(size_t)B * S * H + (size_t)bB * H + t] = hvB;
}

// ---------------------------------------------------------------------------
// Fused persistent kernel, grid = 80 blocks.
//   blocks 0..63  : GEMM workers (dispatched first; never wait -> no deadlock)
//   blocks 64..79 : RNN, batches (2r, 2r+1) for r = bid-64
// ---------------------------------------------------------------------------
__global__ __launch_bounds__(256, 1) void fused_srnn(
    const float* __restrict__ x, const float* __restrict__ Wxw,
    const float* __restrict__ Wxb, const float* __restrict__ Whw,
    float* __restrict__ out, int* __restrict__ flags)
{
    __shared__ __align__(16) float As[TK][LDP];
    __shared__ __align__(16) float Bs[TK][LDP];
    __shared__ __align__(16) _Float16 hshA[2][4][72];
    __shared__ __align__(16) _Float16 hshB[2][4][72];

    const int bid = blockIdx.x;
    const int t   = threadIdx.x;

    if (bid < NWORK) {
        for (int tau = bid; tau < NTILE; tau += NWORK) {
            // s-major order: tau = st*64 + bb*2 + nt
            const int st = tau >> 6;
            const int bb = (tau >> 1) & 31;
            const int nt = tau & 1;
            gemm_tile(x, Wxw, Wxb, out, As, Bs, t,
                      bb * S + st * TM, nt * TN);
            __threadfence();
            __syncthreads();
            if (t == 0)
                __hip_atomic_fetch_add(&flags[bb * 16 + st], 1,
                                       __ATOMIC_RELEASE, __HIP_MEMORY_SCOPE_AGENT);
        }
        return;
    }
    const int r = bid - NWORK;
    rnn_body2(Whw, out, hshA, hshB, 2 * r, 2 * r + 1, t,
              flags + (2 * r) * 16, flags + (2 * r + 1) * 16);
}

// ---------------------------------------------------------------------------
// Fallback path (no workspace): two-kernel pipeline, same bodies.
// ---------------------------------------------------------------------------
__global__ __launch_bounds__(256) void phase1_gemm(
    const float* __restrict__ x, const float* __restrict__ Wxw,
    const float* __restrict__ Wxb, float* __restrict__ out)
{
    __shared__ __align__(16) float As[TK][LDP];
    __shared__ __align__(16) float Bs[TK][LDP];
    gemm_tile(x, Wxw, Wxb, out, As, Bs, threadIdx.x,
              blockIdx.x * TM, blockIdx.y * TN);
}

__global__ __launch_bounds__(256, 1) void phase2_rnn(
    const float* __restrict__ Whw, float* __restrict__ out)
{
    __shared__ __align__(16) _Float16 hshA[2][4][72];
    __shared__ __align__(16) _Float16 hshB[2][4][72];
    const int r = blockIdx.x;
    rnn_body2(Whw, out, hshA, hshB, 2 * r, 2 * r + 1, threadIdx.x,
              nullptr, nullptr);
}

// ---------------------------------------------------------------------------
extern "C" void kernel_launch(void* const* d_in, const int* in_sizes, int n_in,
                              void* d_out, int out_size, void* d_ws, size_t ws_size,
                              hipStream_t stream) {
    const float* x   = (const float*)d_in[0];
    const float* Wxw = (const float*)d_in[1];
    const float* Wxb = (const float*)d_in[2];
    const float* Whw = (const float*)d_in[3];
    float* out = (float*)d_out;

    if (d_ws != nullptr && ws_size >= NFLAG * sizeof(int)) {
        int* flags = (int*)d_ws;
        zero_flags<<<1, NFLAG, 0, stream>>>(flags);
        fused_srnn<<<NWORK + NRNN, 256, 0, stream>>>(x, Wxw, Wxb, Whw, out, flags);
    } else {
        dim3 g1(B * S / TM, H / TN);   // 512 x 2
        phase1_gemm<<<g1, 256, 0, stream>>>(x, Wxw, Wxb, out);
        phase2_rnn<<<NRNN, 256, 0, stream>>>(Whw, out);
    }
}

// Round 15
// 957.943 us; speedup vs baseline: 1.6856x; 1.6689x over previous
//
#include <hip/hip_runtime.h>

#define B 32
#define S 2048
#define I 256
#define H 256

#define NWORK  64     // GEMM worker blocks (bid 0..63). Still >=2x ahead of RNN
                      // demand; half the dense-FMA power of R11 -> less throttle.
#define NRNN   32     // RNN blocks (bid 64..95), one per batch
#define NTILE  1024   // 512 M-tiles x 2 N-tiles
#define NFLAG  512    // 32 batches x 16 s-chunks
#define PFD    8      // xw prefetch depth (steps); 8*H past end stays in-bounds

typedef _Float16 h2 __attribute__((ext_vector_type(2)));
typedef float    f4 __attribute__((ext_vector_type(4)));   // native vec for NT builtins

__device__ __forceinline__ float fdot2(h2 a, h2 b, float c) {
#if __has_builtin(__builtin_amdgcn_fdot2)
    return __builtin_amdgcn_fdot2(a, b, c, false);
#else
    return fmaf((float)a[1], (float)b[1], fmaf((float)a[0], (float)b[0], c));
#endif
}

// NT store of a float4 through the native-vector builtin.
__device__ __forceinline__ void nt_store4(float* p, float4 v) {
    __builtin_nontemporal_store(__builtin_bit_cast(f4, v), (f4*)p);
}

// lgkm-only workgroup barrier. imm 0xC07F = vmcnt(63) expcnt(7) lgkmcnt(0).
__device__ __forceinline__ void lds_barrier() {
    __asm__ __volatile__("" ::: "memory");
    __builtin_amdgcn_s_waitcnt(0xC07F);
    __builtin_amdgcn_s_barrier();
    __asm__ __volatile__("" ::: "memory");
}

// tanh via exp2 with folded constant: tanh(x) = 1 - 2/(1 + 2^(x*2*log2 e)).
__device__ __forceinline__ float fast_tanh(float x) {
#if __has_builtin(__builtin_amdgcn_exp2f) && __has_builtin(__builtin_amdgcn_rcpf)
    float e = __builtin_amdgcn_exp2f(x * 2.8853900818f);   // e^(2x)
    float r = __builtin_amdgcn_rcpf(e + 1.0f);
    return fmaf(-2.0f, r, 1.0f);
#else
    float e = __expf(2.0f * x);
    return 1.0f - __fdividef(2.0f, e + 1.0f);
#endif
}

__device__ __forceinline__ float dpp_xor1(float x) {
    return __builtin_bit_cast(float, __builtin_amdgcn_mov_dpp(
        __builtin_bit_cast(int, x), 0xB1, 0xF, 0xF, false));
}
__device__ __forceinline__ float dpp_xor2(float x) {
    return __builtin_bit_cast(float, __builtin_amdgcn_mov_dpp(
        __builtin_bit_cast(int, x), 0x4E, 0xF, 0xF, false));
}

// Acquire-poll until flag reaches 2 (both N-half producers done).
// Bounded (~0.25 s at the 100 MHz constant clock; normal wait ~30 us): a
// sync bug shows as a correctness failure, never a hung container.
__device__ __forceinline__ void wait_flag(const int* f) {
    long long t0 = __builtin_amdgcn_s_memrealtime();
    while (__hip_atomic_load(f, __ATOMIC_ACQUIRE, __HIP_MEMORY_SCOPE_AGENT) != 2) {
        __builtin_amdgcn_s_sleep(8);
        if (__builtin_amdgcn_s_memrealtime() - t0 > 25000000LL) break;
    }
}

__global__ void zero_flags(int* flags) { flags[threadIdx.x] = 0; }

// ---------------------------------------------------------------------------
// GEMM tile body. xw[m][n] = sum_k x[m][k]*Wxw[n][k] + Wxb[n].
// 128x128 tile, 8x8/thread. NT xw stores: the consumer is on another XCD;
// push lines to memory clean, skip write-allocate pollution.
// ---------------------------------------------------------------------------
#define TM 128
#define TN 128
#define TK 32
#define LDP (TM + 4)

__device__ __forceinline__ void gemm_tile(
    const float* __restrict__ x, const float* __restrict__ Wxw,
    const float* __restrict__ Wxb, float* __restrict__ out,
    float (*As)[LDP], float (*Bs)[LDP], int t, int m0, int n0)
{
    const int lr = t >> 3;    // 0..31
    const int lc = t & 7;     // 0..7
    const int tn = t & 15, tm = t >> 4;

    float acc[8][8] = {};
    float bias[8];
#pragma unroll
    for (int jj = 0; jj < 4; ++jj) {
        bias[jj]     = Wxb[n0 + 4 * tn + jj];
        bias[4 + jj] = Wxb[n0 + 64 + 4 * tn + jj];
    }

    float4 va[4], vb[4];
#pragma unroll
    for (int hh = 0; hh < 4; ++hh) {             // prologue: kt=0
        const int m = lr + 32 * hh;
        va[hh] = *(const float4*)(x   + (size_t)(m0 + m) * I + 4 * lc);
        vb[hh] = *(const float4*)(Wxw + (size_t)(n0 + m) * I + 4 * lc);
    }

    for (int kt = 0; kt < I; kt += TK) {
#pragma unroll
        for (int hh = 0; hh < 4; ++hh) {         // regs -> LDS (transpose)
            const int m = lr + 32 * hh;
            float4 v = va[hh];
            As[4 * lc + 0][m] = v.x; As[4 * lc + 1][m] = v.y;
            As[4 * lc + 2][m] = v.z; As[4 * lc + 3][m] = v.w;
            float4 wv = vb[hh];
            Bs[4 * lc + 0][m] = wv.x; Bs[4 * lc + 1][m] = wv.y;
            Bs[4 * lc + 2][m] = wv.z; Bs[4 * lc + 3][m] = wv.w;
        }
        lds_barrier();
        if (kt + TK < I) {                       // prefetch kt+1
#pragma unroll
            for (int hh = 0; hh < 4; ++hh) {
                const int m = lr + 32 * hh;
                va[hh] = *(const float4*)(x   + (size_t)(m0 + m) * I + kt + TK + 4 * lc);
                vb[hh] = *(const float4*)(Wxw + (size_t)(n0 + m) * I + kt + TK + 4 * lc);
            }
        }
#pragma unroll
        for (int k = 0; k < TK; ++k) {
            float4 a0 = *(const float4*)&As[k][4 * tm];
            float4 a1 = *(const float4*)&As[k][4 * tm + 64];
            float4 b0 = *(const float4*)&Bs[k][4 * tn];
            float4 b1 = *(const float4*)&Bs[k][4 * tn + 64];
            float av[8] = {a0.x, a0.y, a0.z, a0.w, a1.x, a1.y, a1.z, a1.w};
            float bv[8] = {b0.x, b0.y, b0.z, b0.w, b1.x, b1.y, b1.z, b1.w};
#pragma unroll
            for (int i2 = 0; i2 < 8; ++i2)
#pragma unroll
                for (int jj = 0; jj < 8; ++jj)
                    acc[i2][jj] = fmaf(av[i2], bv[jj], acc[i2][jj]);
        }
        lds_barrier();
    }
#pragma unroll
    for (int hi = 0; hi < 2; ++hi) {
#pragma unroll
        for (int i2 = 0; i2 < 4; ++i2) {
            const int r = m0 + 64 * hi + 4 * tm + i2;
            float4 v0 = { acc[4 * hi + i2][0] + bias[0], acc[4 * hi + i2][1] + bias[1],
                          acc[4 * hi + i2][2] + bias[2], acc[4 * hi + i2][3] + bias[3] };
            float4 v1 = { acc[4 * hi + i2][4] + bias[4], acc[4 * hi + i2][5] + bias[5],
                          acc[4 * hi + i2][6] + bias[6], acc[4 * hi + i2][7] + bias[7] };
            nt_store4(out + (size_t)r * H + n0 + 4 * tn,      v0);
            nt_store4(out + (size_t)r * H + n0 + 64 + 4 * tn, v1);
        }
    }
}

// ---------------------------------------------------------------------------
// RNN recurrence body. Math bit-identical to R6-R11. flags==nullptr: no gate.
// Chunk-structured loop: outer 16 chunks x 128 steps; the flag wait exists
// only at sl==120 (the step whose ring prefetch first crosses into chunk
// c+1), keeping the per-step gate check out of the hot loop.
// PFD=8 xw prefetch ring (static indices; 128 % 8 == 0 keeps p/rp static).
// ---------------------------------------------------------------------------
__device__ __forceinline__ void rnn_body(
    const float* __restrict__ Whw, float* __restrict__ out,
    _Float16 (*hsh)[4][72], int b, int t, const int* flags)
{
    const int w = t >> 6;        // wave: rows [64w, 64w+64)
    const int l = t & 63;
    const int j = l >> 2;        // quad: rows 64w+4j .. 64w+4j+3
    const int q = l & 3;         // k-quarter: k in [64q, 64q+64)

    // wreg[i][m] = W[64w+4j+(q^i)][64q + 2m .. 2m+1] as h2 (permuted rows).
    h2 wreg[4][32];
#pragma unroll
    for (int i = 0; i < 4; ++i) {
        const float4* wp =
            (const float4*)(Whw + (size_t)(64 * w + 4 * j + (q ^ i)) * H + 64 * q);
#pragma unroll
        for (int m = 0; m < 16; ++m) {
            float4 f = wp[m];
            wreg[i][2 * m]     = h2{(_Float16)f.x, (_Float16)f.y};
            wreg[i][2 * m + 1] = h2{(_Float16)f.z, (_Float16)f.w};
        }
    }
#pragma unroll
    for (int i = 0; i < 4; ++i)
#pragma unroll
        for (int m = 0; m < 32; ++m) {
            unsigned tmp = __builtin_bit_cast(unsigned, wreg[i][m]);
            __asm__("" : "+v"(tmp));
            wreg[i][m] = __builtin_bit_cast(h2, tmp);
        }

    hsh[0][w][l] = (_Float16)0.0f;
    __syncthreads();

    if (flags) {                        // gate initial xw reads on chunk 0
        if (t == 0) wait_flag(flags + 0);
        __syncthreads();
    }

    float* outb = out + (size_t)b * S * H + t;
    float* op = outb;

    // PFD-deep xw ring. Reads up to PFD steps past the end land in the
    // h_last region / its tail (in bounds for all b; values unused).
    float xr[PFD];
#pragma unroll
    for (int i = 0; i < PFD; ++i) xr[i] = outb[(size_t)i * H];
    const float* lp = outb + (size_t)PFD * H;

    float hv = 0.f;
    for (int c = 0; c < 16; ++c) {       // 16 chunks x 128 steps
#pragma unroll 8
        for (int sl = 0; sl < 128; ++sl) {
            const int p  = sl & 1;           // static (128 % 8 == 0)
            const int rp = sl & (PFD - 1);   // static ring slot
            // The sl==120 iteration's ring refill reads chunk c+1's first
            // element -- gate it. Branch exists only in the sl%8==0 slot.
            if (sl == 120 && c < 15 && flags) {
                if (t == 0) wait_flag(flags + c + 1);
                __syncthreads();
            }
            float xw0 = xr[rp];

            const uint4* hp = (const uint4*)&hsh[p][q][0];
            float acc0 = 0.f, acc1 = 0.f, acc2 = 0.f, acc3 = 0.f;
#pragma unroll
            for (int u = 0; u < 8; ++u) {
                uint4 v = hp[u];
                h2 q0 = __builtin_bit_cast(h2, v.x);
                h2 q1 = __builtin_bit_cast(h2, v.y);
                h2 q2 = __builtin_bit_cast(h2, v.z);
                h2 q3 = __builtin_bit_cast(h2, v.w);
                acc0 = fdot2(wreg[0][4 * u + 0], q0, acc0);
                acc0 = fdot2(wreg[0][4 * u + 1], q1, acc0);
                acc0 = fdot2(wreg[0][4 * u + 2], q2, acc0);
                acc0 = fdot2(wreg[0][4 * u + 3], q3, acc0);
                acc1 = fdot2(wreg[1][4 * u + 0], q0, acc1);
                acc1 = fdot2(wreg[1][4 * u + 1], q1, acc1);
                acc1 = fdot2(wreg[1][4 * u + 2], q2, acc1);
                acc1 = fdot2(wreg[1][4 * u + 3], q3, acc1);
                acc2 = fdot2(wreg[2][4 * u + 0], q0, acc2);
                acc2 = fdot2(wreg[2][4 * u + 1], q1, acc2);
                acc2 = fdot2(wreg[2][4 * u + 2], q2, acc2);
                acc2 = fdot2(wreg[2][4 * u + 3], q3, acc2);
                acc3 = fdot2(wreg[3][4 * u + 0], q0, acc3);
                acc3 = fdot2(wreg[3][4 * u + 1], q1, acc3);
                acc3 = fdot2(wreg[3][4 * u + 2], q2, acc3);
                acc3 = fdot2(wreg[3][4 * u + 3], q3, acc3);
            }

            // Select-free quad butterfly (rows pre-permuted by q^i):
            float Sa  = acc0 + dpp_xor1(acc1);
            float Sb  = acc2 + dpp_xor1(acc3);
            float sum = Sa + dpp_xor2(Sb);   // full sum for row 64w+l == t

            hv = fast_tanh(xw0 + sum);
            hsh[p ^ 1][w][l] = (_Float16)hv; // publish first (lgkm path)
            op[0] = hv;                      // outputs[b,s,t] (normal store)
            op += H;
            xr[rp] = lp[0]; lp += H;         // refill ring: step s+PFD

            lds_barrier();                   // the ONE barrier per step
        }
    }
    out[(size_t)B * S * H + (size_t)b * H + t] = hv;   // h_last
}

// ---------------------------------------------------------------------------
// Fused persistent kernel, grid = 96 blocks (<= 1 per CU; only 96 of 256 CUs
// powered to limit clock throttle during the worker window).
//   blocks 0..63  : GEMM workers (dispatched first; never wait -> no deadlock)
//   blocks 64..95 : RNN (batch = bid-64), t0 acquire-polls chunk flags
// ---------------------------------------------------------------------------
__global__ __launch_bounds__(256, 1) void fused_srnn(
    const float* __restrict__ x, const float* __restrict__ Wxw,
    const float* __restrict__ Wxb, const float* __restrict__ Whw,
    float* __restrict__ out, int* __restrict__ flags)
{
    __shared__ __align__(16) float As[TK][LDP];
    __shared__ __align__(16) float Bs[TK][LDP];
    __shared__ __align__(16) _Float16 hsh[2][4][72];

    const int bid = blockIdx.x;
    const int t   = threadIdx.x;

    if (bid < NWORK) {
        for (int tau = bid; tau < NTILE; tau += NWORK) {
            // s-major order: tau = st*64 + bb*2 + nt
            const int st = tau >> 6;
            const int bb = (tau >> 1) & 31;
            const int nt = tau & 1;
            gemm_tile(x, Wxw, Wxb, out, As, Bs, t,
                      bb * S + st * TM, nt * TN);
            // publish this (batch, s-chunk) half: fence own stores, sync, add.
            __threadfence();
            __syncthreads();
            if (t == 0)
                __hip_atomic_fetch_add(&flags[bb * 16 + st], 1,
                                       __ATOMIC_RELEASE, __HIP_MEMORY_SCOPE_AGENT);
        }
        return;
    }
    rnn_body(Whw, out, hsh, bid - NWORK, t, flags + (bid - NWORK) * 16);
}

// ---------------------------------------------------------------------------
// Fallback path (no workspace): the proven two-kernel pipeline.
// ---------------------------------------------------------------------------
__global__ __launch_bounds__(256) void phase1_gemm(
    const float* __restrict__ x, const float* __restrict__ Wxw,
    const float* __restrict__ Wxb, float* __restrict__ out)
{
    __shared__ __align__(16) float As[TK][LDP];
    __shared__ __align__(16) float Bs[TK][LDP];
    gemm_tile(x, Wxw, Wxb, out, As, Bs, threadIdx.x,
              blockIdx.x * TM, blockIdx.y * TN);
}

__global__ __launch_bounds__(256, 1) void phase2_rnn(
    const float* __restrict__ Whw, float* __restrict__ out)
{
    __shared__ __align__(16) _Float16 hsh[2][4][72];
    rnn_body(Whw, out, hsh, blockIdx.x, threadIdx.x, nullptr);
}

// ---------------------------------------------------------------------------
extern "C" void kernel_launch(void* const* d_in, const int* in_sizes, int n_in,
                              void* d_out, int out_size, void* d_ws, size_t ws_size,
                              hipStream_t stream) {
    const float* x   = (const float*)d_in[0];
    const float* Wxw = (const float*)d_in[1];
    const float* Wxb = (const float*)d_in[2];
    const float* Whw = (const float*)d_in[3];
    float* out = (float*)d_out;

    if (d_ws != nullptr && ws_size >= NFLAG * sizeof(int)) {
        int* flags = (int*)d_ws;
        zero_flags<<<1, NFLAG, 0, stream>>>(flags);
        fused_srnn<<<NWORK + NRNN, 256, 0, stream>>>(x, Wxw, Wxb, Whw, out, flags);
    } else {
        dim3 g1(B * S / TM, H / TN);   // 512 x 2
        phase1_gemm<<<g1, 256, 0, stream>>>(x, Wxw, Wxb, out);
        phase2_rnn<<<B, 256, 0, stream>>>(Whw, out);
    }
}